// Round 7
// baseline (632.936 us; speedup 1.0000x reference)
//
#include <hip/hip_runtime.h>

#define IN_DIM 128
#define OUT_DIM 64
#define CAP 16

// ---- Build: fixed-capacity buckets. cursor[] pre-zeroed via hipMemsetAsync.
// cursor[P] doubles as the overflow counter. (Proven in R6.) ----
__global__ void scatter_kernel(const int* __restrict__ idx,
                               int* __restrict__ cursor,    // [P+1]
                               int* __restrict__ bucket,    // [P*CAP]
                               int* __restrict__ overflow,  // [E]
                               int E, int P) {
    int e = blockIdx.x * 256 + threadIdx.x;
    if (e < E) {
        int p = idx[e];
        int pos = atomicAdd(&cursor[p], 1);
        if (pos < CAP) bucket[p * CAP + pos] = e;
        else           overflow[atomicAdd(&cursor[P], 1)] = e;
    }
}

// ---- Main: one wave per bucket slot; no LDS, no barriers. Lane l at step k
// loads W.flat[k*256 + 4l .. +3] (wave-contiguous 1 KB -> 8 L2 requests,
// vs 64 for row-strided). That covers rows 2k (lanes 0-31) and 2k+1
// (lanes 32-63); each lane dots with its own x[4*(lane&31)..] chunk, then a
// 5-step half-wave butterfly + one cross-half exchange yields both row sums,
// deposited into the accumulator lane matching the row. Same-entry waves are
// adjacent in slot order; the bijective XCD swizzle keeps them on one XCD so
// W[p] is fetched from HBM once and repeats hit that XCD's L2/L1. ----
__global__ __launch_bounds__(256) void wave_gemv_kernel(
    const float* __restrict__ x,        // [E,128]
    const float* __restrict__ Wpool,    // [P,64,128]
    const float* __restrict__ bpool,    // [P,64]
    float*       __restrict__ out,      // [E,64]
    const int*   __restrict__ cursor,   // [P+1]
    const int*   __restrict__ bucket,   // [P*CAP]
    int P)
{
    // bijective XCD-aware block swizzle (m204 form; exact when G%8==0)
    const int G   = gridDim.x;
    const int bid = blockIdx.x;
    const int q = G >> 3, r = G & 7;
    const int xcd = bid & 7;
    const int swz = (xcd < r ? xcd * (q + 1) : r * (q + 1) + (xcd - r) * q)
                    + (bid >> 3);

    const int s = swz * 4 + (threadIdx.x >> 6);   // slot id
    const int p = s >> 4;                         // slot / CAP
    const int j = s & (CAP - 1);
    if (p >= P) return;

    int n = cursor[p];
    n = (n > CAP) ? CAP : n;
    if (j >= n) return;                           // empty slot, cheap exit

    const int e    = bucket[p * CAP + j];
    const int lane = threadIdx.x & 63;

    // this lane's x chunk (lanes 32-63 duplicate lanes 0-31 -> L1 hit)
    const float4 xq = *reinterpret_cast<const float4*>(
        x + (size_t)e * IN_DIM + ((lane & 31) << 2));

    const float* Wp = Wpool + (size_t)p * (OUT_DIM * IN_DIM);
    float acc = 0.f;

    #pragma unroll 4
    for (int k = 0; k < 32; ++k) {
        // flat-coalesced: 64 lanes x 16B = 1 KB contiguous
        const float4 w = *reinterpret_cast<const float4*>(
            Wp + (k << 8) + (lane << 2));
        float rsum = w.x * xq.x + w.y * xq.y + w.z * xq.z + w.w * xq.w;
        // half-wave butterfly: each 32-lane half sums its row
        rsum += __shfl_xor(rsum, 1);
        rsum += __shfl_xor(rsum, 2);
        rsum += __shfl_xor(rsum, 4);
        rsum += __shfl_xor(rsum, 8);
        rsum += __shfl_xor(rsum, 16);
        const float rother = __shfl_xor(rsum, 32);
        // low half holds row 2k, high half holds row 2k+1
        const float lowSum  = (lane < 32) ? rsum : rother;
        const float highSum = (lane < 32) ? rother : rsum;
        acc = (lane == 2 * k)     ? lowSum  : acc;
        acc = (lane == 2 * k + 1) ? highSum : acc;
    }

    acc += bpool[(size_t)p * OUT_DIM + lane];
    out[(size_t)e * OUT_DIM + lane] = fmaxf(acc, 0.f);   // coalesced 256 B
}

// ---- Overflow fallback (bucket fuller than CAP; ~0 edges expected at
// Poisson(5) with CAP=16, but correct in principle). ----
__global__ void overflow_kernel(const float* __restrict__ x,
                                const float* __restrict__ Wpool,
                                const float* __restrict__ bpool,
                                float* __restrict__ out,
                                const int* __restrict__ cursor,
                                const int* __restrict__ overflow,
                                const int* __restrict__ idx, int P, int E) {
    int nov = cursor[P];
    nov = (nov < E) ? nov : E;
    const int lane = threadIdx.x & 63;
    const int wv = (blockIdx.x * blockDim.x + threadIdx.x) >> 6;
    const int nw = (gridDim.x * blockDim.x) >> 6;
    for (int w = wv; w < nov; w += nw) {
        const int e = overflow[w];
        const int p = idx[e];
        const float* Wrow = Wpool + (size_t)p * (OUT_DIM * IN_DIM)
                                  + (size_t)lane * IN_DIM;
        const float* xe = x + (size_t)e * IN_DIM;
        float acc = 0.f;
        #pragma unroll 8
        for (int i = 0; i < IN_DIM; i += 4) {
            const float4 wq = *reinterpret_cast<const float4*>(Wrow + i);
            const float4 xv = *reinterpret_cast<const float4*>(xe + i);
            acc += wq.x * xv.x + wq.y * xv.y + wq.z * xv.z + wq.w * xv.w;
        }
        acc += bpool[(size_t)p * OUT_DIM + lane];
        out[(size_t)e * OUT_DIM + lane] = fmaxf(acc, 0.f);
    }
}

extern "C" void kernel_launch(void* const* d_in, const int* in_sizes, int n_in,
                              void* d_out, int out_size, void* d_ws, size_t ws_size,
                              hipStream_t stream) {
    const float* x    = (const float*)d_in[0];   // [E,128,1]
    const int*   idx  = (const int*)d_in[1];     // [E]
    const float* W    = (const float*)d_in[2];   // [P,64,128]
    const float* b    = (const float*)d_in[3];   // [P,64,1]
    float* out = (float*)d_out;                  // [E,64,1] fp32

    const int E = in_sizes[1];
    const int P = in_sizes[2] / (OUT_DIM * IN_DIM);

    int* cursor   = (int*)d_ws;                  // P+1 (last = overflow count)
    int* bucket   = cursor + (P + 1);            // P*CAP
    int* overflow = bucket + (size_t)P * CAP;    // E

    hipMemsetAsync(cursor, 0, (size_t)(P + 1) * sizeof(int), stream);
    scatter_kernel<<<(E + 255) / 256, 256, 0, stream>>>(idx, cursor, bucket,
                                                        overflow, E, P);
    const int slots  = P * CAP;
    const int blocks = (slots + 3) / 4;          // 4 waves (slots) per block
    wave_gemv_kernel<<<blocks, 256, 0, stream>>>(x, W, b, out, cursor, bucket, P);
    overflow_kernel<<<8, 256, 0, stream>>>(x, W, b, out, cursor, overflow,
                                           idx, P, E);
}

// Round 8
// 477.595 us; speedup vs baseline: 1.3253x; 1.3253x over previous
//
#include <hip/hip_runtime.h>

#define IN_DIM 128
#define OUT_DIM 64
#define CAP 16

// ---- Build: fixed-capacity buckets. cursor[] pre-zeroed via hipMemsetAsync.
// cursor[P] doubles as the overflow counter. (R6/R7-proven.) ----
__global__ void scatter_kernel(const int* __restrict__ idx,
                               int* __restrict__ cursor,    // [P+1]
                               int* __restrict__ bucket,    // [P*CAP]
                               int* __restrict__ overflow,  // [E]
                               int E, int P) {
    int e = blockIdx.x * 256 + threadIdx.x;
    if (e < E) {
        int p = idx[e];
        int pos = atomicAdd(&cursor[p], 1);
        if (pos < CAP) bucket[p * CAP + pos] = e;
        else           overflow[atomicAdd(&cursor[P], 1)] = e;
    }
}

// ---- Main: one block per pool entry. W[p] streamed ONCE through registers
// in 8 coalesced passes (256 threads x float4 = 4 KB/pass); each in-register
// W fragment is reused across all n bucket edges before the next pass.
// Per (pass, edge): 4 FMA + 3 shfl (8-lane group reduce) + 1 masked LDS
// write. Row r = 8i + (t>>5) is written exactly once -> no acc zero-init.
// Final: per edge, lane o sums acc[e][o][0..3] (+1 pad kills conflicts),
// adds bias, relu, coalesced 256 B store. 2 barriers per block, no vmcnt
// drain of a 32 KB stage, 5 blocks/CU. ----
__global__ __launch_bounds__(256) void entry_gemv_kernel(
    const float* __restrict__ x,        // [E,128]
    const float* __restrict__ Wpool,    // [P,64,128]
    const float* __restrict__ bpool,    // [P,64]
    float*       __restrict__ out,      // [E,64]
    const int*   __restrict__ cursor,   // [P+1]
    const int*   __restrict__ bucket,   // [P*CAP]
    int P)
{
    __shared__ float xs[CAP][IN_DIM];          // 8 KB
    __shared__ float acc[CAP][OUT_DIM][5];     // 20.5 KB (pad 5: bank-safe)

    const int p = blockIdx.x;
    int n = cursor[p];
    n = (n > CAP) ? CAP : n;
    if (n == 0) return;                        // uniform exit before barriers

    const int t    = threadIdx.x;
    const int wv   = t >> 6;
    const int lane = t & 63;

    // Stage x for the bucket's edges (wave e: coalesced 512 B per edge).
    for (int e = wv; e < n; e += 4) {
        const int eid = bucket[p * CAP + e];
        reinterpret_cast<float2*>(xs[e])[lane] =
            reinterpret_cast<const float2*>(x + (size_t)eid * IN_DIM)[lane];
    }
    __syncthreads();

    const float* Wp = Wpool + (size_t)p * (OUT_DIM * IN_DIM);
    const int  m      = t & 31;                // column-chunk (float4 index)
    const int  g      = (lane >> 3) & 3;       // slot within row
    const bool writer = (lane & 7) == 0;
    const int  rbase  = t >> 5;                // 0..7: row offset within pass

    // Pass i covers rows 8i..8i+7; thread t holds W[row][4m..4m+3].
    float4 w = *reinterpret_cast<const float4*>(Wp + 4 * t);
    #pragma unroll
    for (int i = 0; i < 8; ++i) {
        float4 wn;
        if (i < 7)                              // prefetch next pass's fragment
            wn = *reinterpret_cast<const float4*>(Wp + (i + 1) * 1024 + 4 * t);
        const int row = i * 8 + rbase;
        for (int e = 0; e < n; ++e) {
            const float4 xq = reinterpret_cast<const float4*>(xs[e])[m];
            float ps = w.x * xq.x + w.y * xq.y + w.z * xq.z + w.w * xq.w;
            ps += __shfl_xor(ps, 1);
            ps += __shfl_xor(ps, 2);
            ps += __shfl_xor(ps, 4);
            if (writer) acc[e][row][g] = ps;    // 8 contiguous floats/wave
        }
        w = wn;
    }
    __syncthreads();

    const float bv = bpool[(size_t)p * OUT_DIM + lane];
    for (int e = wv; e < n; e += 4) {
        const int eid = bucket[p * CAP + e];
        const float* a = acc[e][lane];          // stride-5 rows: conflict-free
        const float s = (a[0] + a[1]) + (a[2] + a[3]) + bv;
        out[(size_t)eid * OUT_DIM + lane] = fmaxf(s, 0.f);
    }
}

// ---- Overflow fallback (bucket fuller than CAP; ~0 edges expected, but
// correct in principle). ----
__global__ void overflow_kernel(const float* __restrict__ x,
                                const float* __restrict__ Wpool,
                                const float* __restrict__ bpool,
                                float* __restrict__ out,
                                const int* __restrict__ cursor,
                                const int* __restrict__ overflow,
                                const int* __restrict__ idx, int P, int E) {
    int nov = cursor[P];
    nov = (nov < E) ? nov : E;
    const int lane = threadIdx.x & 63;
    const int wv = (blockIdx.x * blockDim.x + threadIdx.x) >> 6;
    const int nw = (gridDim.x * blockDim.x) >> 6;
    for (int w = wv; w < nov; w += nw) {
        const int e = overflow[w];
        const int p = idx[e];
        const float* Wrow = Wpool + (size_t)p * (OUT_DIM * IN_DIM)
                                  + (size_t)lane * IN_DIM;
        const float* xe = x + (size_t)e * IN_DIM;
        float acc2 = 0.f;
        #pragma unroll 8
        for (int i = 0; i < IN_DIM; i += 4) {
            const float4 wq = *reinterpret_cast<const float4*>(Wrow + i);
            const float4 xv = *reinterpret_cast<const float4*>(xe + i);
            acc2 += wq.x * xv.x + wq.y * xv.y + wq.z * xv.z + wq.w * xv.w;
        }
        acc2 += bpool[(size_t)p * OUT_DIM + lane];
        out[(size_t)e * OUT_DIM + lane] = fmaxf(acc2, 0.f);
    }
}

extern "C" void kernel_launch(void* const* d_in, const int* in_sizes, int n_in,
                              void* d_out, int out_size, void* d_ws, size_t ws_size,
                              hipStream_t stream) {
    const float* x    = (const float*)d_in[0];   // [E,128,1]
    const int*   idx  = (const int*)d_in[1];     // [E]
    const float* W    = (const float*)d_in[2];   // [P,64,128]
    const float* b    = (const float*)d_in[3];   // [P,64,1]
    float* out = (float*)d_out;                  // [E,64,1] fp32

    const int E = in_sizes[1];
    const int P = in_sizes[2] / (OUT_DIM * IN_DIM);

    int* cursor   = (int*)d_ws;                  // P+1 (last = overflow count)
    int* bucket   = cursor + (P + 1);            // P*CAP
    int* overflow = bucket + (size_t)P * CAP;    // E

    hipMemsetAsync(cursor, 0, (size_t)(P + 1) * sizeof(int), stream);
    scatter_kernel<<<(E + 255) / 256, 256, 0, stream>>>(idx, cursor, bucket,
                                                        overflow, E, P);
    entry_gemv_kernel<<<P, 256, 0, stream>>>(x, W, b, out, cursor, bucket, P);
    overflow_kernel<<<8, 256, 0, stream>>>(x, W, b, out, cursor, overflow,
                                           idx, P, E);
}